// Round 2
// baseline (1463.742 us; speedup 1.0000x reference)
//
#include <hip/hip_runtime.h>
#include <math.h>

constexpr int NB = 32, NT = 64, ND = 32, NH = 256, NZ = 64, NG = 768;

// ---- ws layout (float offsets; u16 regions noted) --------------------------
constexpr long long OFF_EWHHT  = 0;                              // [256][768] f32 (enc Whh^T, k-major)
constexpr long long OFF_EWIHT  = OFF_EWHHT + NH * NG;            // [32][768] f32
constexpr long long OFF_GIENC  = OFF_EWIHT + 32 * NG;            // [2048][768] f32
constexpr long long OFF_HENC   = OFF_GIENC + (long long)NB * NT * NG;
constexpr long long OFF_H0     = OFF_HENC + NB * NH;             // [32][256] f32
constexpr long long OFF_HDEC   = OFF_H0 + NB * NH;               // [32d][32b][256] f32 master h
constexpr long long OFF_BCMB   = OFF_HDEC + (long long)ND * NB * NH; // [32d][2][256] (bih+bhh for r,z)
constexpr long long OFF_BIN    = OFF_BCMB + ND * 2 * NH;         // [32d][256] bih_n
constexpr long long OFF_BHN    = OFF_BIN + ND * NH;              // [32d][256] bhh_n
constexpr long long OFF_WHHIMG = OFF_BHN + ND * NH;              // u16: 256 pages x 24576 (swizzled bf16)
constexpr long long OFF_WCIMG  = OFF_WHHIMG + (long long)256 * 24576 / 2; // u16: 256 pages x 3072
constexpr long long OFF_DINIMG = OFF_WCIMG + 256 * 3072 / 2;     // u16: 64 pages x 1024
constexpr long long OFF_HBF    = OFF_DINIMG + 64 * 1024 / 2;     // u16: 2 par x 32 d x 8192 (swizzled bf16 h)
constexpr long long WS_FLOATS  = OFF_HBF + 2 * 32 * 8192 / 2;    // ~23.8 MB

typedef __attribute__((ext_vector_type(8))) short bf16x8;
typedef __attribute__((ext_vector_type(4))) float f32x4;

__device__ __forceinline__ float sigm(float x) { return 1.f / (1.f + __expf(-x)); }
__device__ __forceinline__ ushort f2b(float x) {
  unsigned u = __float_as_uint(x);
  unsigned r = (u + 0x7FFFu + ((u >> 16) & 1u)) >> 16;
  return (ushort)r;
}

// ---------------- k_pre: encoder transposes + decoder Whh images + biases ----
__global__ void k_pre(const float* __restrict__ hWhh, const float* __restrict__ hbih,
                      const float* __restrict__ hbhh, const float* __restrict__ eWhh,
                      const float* __restrict__ eWih, float* __restrict__ ws) {
  int stride = gridDim.x * blockDim.x;
  int idx = blockIdx.x * blockDim.x + threadIdx.x;
  // (1) encoder Whh^T [k][g]
  for (int i = idx; i < NH * NG; i += stride) {
    int k = i / NG, g = i - k * NG;
    ws[OFF_EWHHT + i] = eWhh[g * NH + k];
  }
  // (2) encoder Wih^T [k][g]
  for (int i = idx; i < 32 * NG; i += stride) {
    int k = i / NG, g = i - k * NG;
    ws[OFF_EWIHT + i] = eWih[g * 32 + k];
  }
  // (3) decoder Whh bf16 swizzled images: 256 pages x 12288 dwords
  unsigned* img = (unsigned*)(ws + OFF_WHHIMG);
  const int totw = 256 * 12288;
  for (int i = idx; i < totw; i += stride) {
    int p = i / 12288, lw = i - p * 12288;
    int d = p >> 3, s = p & 7;
    int byte = lw * 4;
    int lr = byte >> 9;                        // local row 0..95
    int nominal = byte ^ ((lr & 7) << 4);
    int k0 = (nominal & 511) >> 1;             // even
    int g = (lr >> 5) * 256 + s * 32 + (lr & 31);
    const float* src = hWhh + ((long long)(d * NG + g)) * NH + k0;
    unsigned lo = f2b(src[0]), hi = f2b(src[1]);
    img[i] = lo | (hi << 16);
  }
  // (4) biases
  for (int i = idx; i < ND * NH; i += stride) {
    int d = i >> 8, j = i & 255;
    const float* bi = hbih + d * NG;
    const float* bh = hbhh + d * NG;
    ws[OFF_BCMB + d * 512 + j]       = bi[j] + bh[j];
    ws[OFF_BCMB + d * 512 + 256 + j] = bi[256 + j] + bh[256 + j];
    ws[OFF_BIN + i] = bi[512 + j];
    ws[OFF_BHN + i] = bh[512 + j];
  }
}

// ---------------- k_wcomb: Wcomb[d][g][dd] = sum_h Wih[g,h]*Win[dd,h] -> bf16 image
__global__ __launch_bounds__(256)
void k_wcomb(const float* __restrict__ Win, const float* __restrict__ hWih,
             float* __restrict__ ws) {
  __shared__ float wd_s[32 * 257];
  __shared__ float wih_s[32 * 257];
  int blk = blockIdx.x;            // 768 = 32 d x 24 gsec
  int d = blk / 24, gsec = blk - d * 24;
  int tid = threadIdx.x;
  for (int i = tid; i < 32 * 256; i += 256) {
    int r = i >> 8, h = i & 255;
    wd_s[r * 257 + h]  = Win[((long long)(d * 32 + r)) * 256 + h];
    wih_s[r * 257 + h] = hWih[((long long)(d * NG + gsec * 32 + r)) * 256 + h];
  }
  __syncthreads();
  ushort* wcimg = (ushort*)(ws + OFF_WCIMG);
  for (int o = tid; o < 1024; o += 256) {
    int gl = o >> 5, dd = o & 31;
    float acc = 0.f;
    #pragma unroll 4
    for (int h = 0; h < 256; ++h) acc += wih_s[gl * 257 + h] * wd_s[dd * 257 + h];
    int gloc = gsec * 32 + gl;                 // 0..767
    int sec = gloc >> 8, s = (gloc & 255) >> 5, lr = sec * 32 + (gloc & 31);
    int off = (lr * 64 + dd * 2) ^ ((lr & 3) << 4);
    wcimg[(d * 8 + s) * 3072 + (off >> 1)] = f2b(acc);
  }
}

// ---------------- k_misc: recon init (fc_b) + din bf16 swizzled pages --------
__global__ void k_misc(const float* __restrict__ xp, const float* __restrict__ xc,
                       const float* __restrict__ fcb, float* __restrict__ ws,
                       float* __restrict__ out) {
  int idx = blockIdx.x * blockDim.x + threadIdx.x;   // 0..98303
  if (idx < 65536) {
    out[idx] = fcb[idx & 31];
  } else {
    int i2 = idx - 65536;                      // 64 t x 512 dwords
    int t = i2 >> 9, lw = i2 & 511;
    int byte = lw * 4;
    int b = byte >> 6;
    int nominal = byte ^ ((b & 3) << 4);
    int dd0 = (nominal & 63) >> 1;             // even
    float v0, v1;
    if (t == 0) {
      v0 = xp[(b * NT + 63) * ND + dd0];
      v1 = xp[(b * NT + 63) * ND + dd0 + 1];
    } else {
      v0 = xc[(b * NT + (t - 1)) * ND + dd0];
      v1 = xc[(b * NT + (t - 1)) * ND + dd0 + 1];
    }
    unsigned lo = f2b(v0), hi = f2b(v1);
    ((unsigned*)(ws + OFF_DINIMG))[i2] = lo | (hi << 16);
  }
}

// ---------------- encoder input gates ---------------------------------------
__global__ void k_gi_enc(const float* __restrict__ xp, const float* __restrict__ bih,
                         float* __restrict__ ws) {
  __shared__ float xs[32];
  int bt = blockIdx.x, tid = threadIdx.x;      // 256
  if (tid < 32) xs[tid] = xp[bt * 32 + tid];
  __syncthreads();
  const float* WT = ws + OFF_EWIHT;
  float a0 = 0.f, a1 = 0.f, a2 = 0.f;
  #pragma unroll
  for (int k = 0; k < 32; ++k) {
    float x = xs[k];
    a0 += WT[k * NG + tid      ] * x;
    a1 += WT[k * NG + tid + 256] * x;
    a2 += WT[k * NG + tid + 512] * x;
  }
  float* gi = ws + OFF_GIENC + (long long)bt * NG;
  gi[tid      ] = a0 + bih[tid      ];
  gi[tid + 256] = a1 + bih[tid + 256];
  gi[tid + 512] = a2 + bih[tid + 512];
}

// ---------------- encoder GRU (1 block / batch) ------------------------------
__global__ __launch_bounds__(256)
void k_enc(const float* __restrict__ bhh, float* __restrict__ ws) {
  __shared__ float h[NH];
  int b = blockIdx.x, tid = threadIdx.x;
  h[tid] = 0.f;
  __syncthreads();
  const float* WT = ws + OFF_EWHHT;
  const float* gi_base = ws + OFF_GIENC + (long long)b * NT * NG;
  for (int t = 0; t < NT; ++t) {
    const float* gi = gi_base + t * NG;
    float a0 = 0.f, a1 = 0.f, a2 = 0.f;
    #pragma unroll 4
    for (int k = 0; k < NH; ++k) {
      float hv = h[k];
      a0 += WT[k * NG + tid      ] * hv;
      a1 += WT[k * NG + tid + 256] * hv;
      a2 += WT[k * NG + tid + 512] * hv;
    }
    float ir = gi[tid], iz = gi[tid + 256], in = gi[tid + 512];
    float hr = a0 + bhh[tid], hz = a1 + bhh[tid + 256], hn = a2 + bhh[tid + 512];
    float r = sigm(ir + hr);
    float u = sigm(iz + hz);
    float n = tanhf(in + r * hn);
    __syncthreads();
    float hnew = (1.f - u) * n + u * h[tid];
    h[tid] = hnew;
    __syncthreads();
  }
  ws[OFF_HENC + b * NH + tid] = h[tid];
}

// ---------------- latent ------------------------------------------------------
__global__ __launch_bounds__(256)
void k_latent(const float* __restrict__ muw, const float* __restrict__ mub,
              const float* __restrict__ lsw, const float* __restrict__ lsb,
              const float* __restrict__ refw, const float* __restrict__ refb,
              const float* __restrict__ eps, float* __restrict__ ws,
              float* __restrict__ out) {
  __shared__ float hs[NH];
  __shared__ float mu_s[NZ];
  __shared__ float ls_s[NZ];
  __shared__ float zs[NZ];
  int b = blockIdx.x, tid = threadIdx.x;
  hs[tid] = ws[OFF_HENC + b * NH + tid];
  __syncthreads();
  if (tid < 128) {
    int zi = tid & 63;
    const float* w = (tid < 64 ? muw : lsw) + zi * NH;
    float acc = 0.f;
    #pragma unroll 4
    for (int k = 0; k < NH; ++k) acc += w[k] * hs[k];
    if (tid < 64) {
      acc += mub[zi];
      out[NB * NT * ND + b * NZ + zi] = acc;
      mu_s[zi] = acc;
    } else {
      acc += lsb[zi];
      out[NB * NT * ND + NB * NZ + b * NZ + zi] = acc;
      ls_s[zi] = acc;
    }
  }
  __syncthreads();
  if (tid < 64) zs[tid] = mu_s[tid] + eps[b * NZ + tid] * __expf(ls_s[tid]);
  __syncthreads();
  {
    const float* w = refw + tid * NZ;
    float acc = 0.f;
    #pragma unroll 4
    for (int q = 0; q < NZ; ++q) acc += w[q] * zs[q];
    ws[OFF_H0 + b * NH + tid] = tanhf(acc + refb[tid]);
  }
}

// ---------------- k_hbf0: h0 -> bf16 swizzled pages (parity 0, all heads) ----
__global__ void k_hbf0(float* __restrict__ ws) {
  int idx = blockIdx.x * blockDim.x + threadIdx.x;   // 32 pages x 4096 dwords
  int d = idx >> 12, lw = idx & 4095;
  int byte = lw * 4;
  int bb = byte >> 9;
  int nominal = byte ^ ((bb & 7) << 4);
  int j0 = (nominal & 511) >> 1;
  const float* h0 = ws + OFF_H0 + bb * 256;
  unsigned lo = f2b(h0[j0]), hi = f2b(h0[j0 + 1]);
  ((unsigned*)(ws + OFF_HBF))[d * 4096 + lw] = lo | (hi << 16);
}

// ---------------- decoder step: 256 blocks = 8 slices x 32 heads, 384 thr ----
__global__ __launch_bounds__(384)
void k_step2(const float* __restrict__ fcw, float* __restrict__ ws,
             float* __restrict__ out, int t) {
  __shared__ __align__(16) char lds[49152 + 6144 + 16384 + 2048];
  __shared__ float rz_s[64 * 33];
  __shared__ float in_s[32 * 33];
  __shared__ float ahn_s[32 * 33];
  __shared__ float hn_s[32 * 33];

  char* l_whh = lds;
  char* l_wc  = lds + 49152;
  char* l_hbf = lds + 49152 + 6144;
  char* l_din = lds + 49152 + 6144 + 16384;

  const int d = blockIdx.x & 31, s = blockIdx.x >> 5;
  const int tid = threadIdx.x, lane = tid & 63, w = tid >> 6;

  const ushort* whh_img = (const ushort*)(ws + OFF_WHHIMG) + (long long)(d * 8 + s) * 24576;
  const ushort* wc_img  = (const ushort*)(ws + OFF_WCIMG) + (d * 8 + s) * 3072;
  const ushort* hbf_r   = (const ushort*)(ws + OFF_HBF) + ((t & 1) * 32 + d) * 8192;
  const ushort* din_img = (const ushort*)(ws + OFF_DINIMG) + t * 1024;

  {  // staging: 4608 x 16B chunks (linear; images pre-swizzled)
    const uint4* s_whh = (const uint4*)whh_img;
    const uint4* s_wc  = (const uint4*)wc_img;
    const uint4* s_hbf = (const uint4*)hbf_r;
    const uint4* s_din = (const uint4*)din_img;
    uint4* d_whh = (uint4*)l_whh; uint4* d_wc = (uint4*)l_wc;
    uint4* d_hbf = (uint4*)l_hbf; uint4* d_din = (uint4*)l_din;
    for (int c = tid; c < 4608; c += 384) {
      if (c < 3072)      d_whh[c] = s_whh[c];
      else if (c < 3456) d_wc[c - 3072] = s_wc[c - 3072];
      else if (c < 4480) d_hbf[c - 3456] = s_hbf[c - 3456];
      else               d_din[c - 4480] = s_din[c - 4480];
    }
  }
  __syncthreads();

  // MFMA: 6 waves x (2 row-tiles x 1 col-tile); A rows = gates, B cols = batch
  const int ct = w & 1, rtb = w >> 1;
  const int colL = lane & 15;
  const int kb = (lane >> 4) * 16;            // k-octet byte offset
  #pragma unroll
  for (int i = 0; i < 2; ++i) {
    int rtx = rtb + 3 * i;
    int rowW = rtx * 16 + colL;
    int rowB = ct * 16 + colL;                // batch index
    f32x4 ah = {0.f, 0.f, 0.f, 0.f};
    #pragma unroll
    for (int kc = 0; kc < 8; ++kc) {
      int ka = kc * 64 + kb;
      bf16x8 av = *(const bf16x8*)(l_whh + (((rowW * 512 + ka)) ^ ((rowW & 7) << 4)));
      bf16x8 bv = *(const bf16x8*)(l_hbf + (((rowB * 512 + ka)) ^ ((rowB & 7) << 4)));
      ah = __builtin_amdgcn_mfma_f32_16x16x32_bf16(av, bv, ah, 0, 0, 0);
    }
    f32x4 zero = {0.f, 0.f, 0.f, 0.f};
    bf16x8 aw = *(const bf16x8*)(l_wc + (((rowW * 64 + kb)) ^ ((rowW & 3) << 4)));
    bf16x8 bd = *(const bf16x8*)(l_din + (((rowB * 64 + kb)) ^ ((rowB & 3) << 4)));
    f32x4 ai = __builtin_amdgcn_mfma_f32_16x16x32_bf16(aw, bd, zero, 0, 0, 0);
    int r0 = rtx * 16 + (lane >> 4) * 4;
    int col = ct * 16 + colL;
    #pragma unroll
    for (int rg = 0; rg < 4; ++rg) {
      int lr = r0 + rg;
      if (lr < 64) rz_s[lr * 33 + col] = ah[rg] + ai[rg];
      else { in_s[(lr - 64) * 33 + col] = ai[rg]; ahn_s[(lr - 64) * 33 + col] = ah[rg]; }
    }
  }
  __syncthreads();

  // gate math + h update (1024 items)
  const float* bcmb = ws + OFF_BCMB + d * 512;
  const float* bin  = ws + OFF_BIN + d * 256;
  const float* bhn  = ws + OFF_BHN + d * 256;
  float* hdec = ws + OFF_HDEC + (long long)d * NB * NH;
  const float* h0 = ws + OFF_H0;
  ushort* hbf_w = (ushort*)(ws + OFF_HBF) + (((t + 1) & 1) * 32 + d) * 8192;

  for (int base = 0; base < 1024; base += 384) {
    int idx = base + tid;
    if (idx < 1024) {
      int bb = idx >> 5, jl = idx & 31, jg = s * 32 + jl;
      float pr = rz_s[jl * 33 + bb] + bcmb[jg];
      float pz = rz_s[(32 + jl) * 33 + bb] + bcmb[256 + jg];
      float pni = in_s[jl * 33 + bb] + bin[jg];
      float pnh = ahn_s[jl * 33 + bb] + bhn[jg];
      float r = sigm(pr), u = sigm(pz);
      float n = tanhf(pni + r * pnh);
      float hold = (t == 0) ? h0[bb * 256 + jg] : hdec[bb * 256 + jg];
      float hnew = (1.f - u) * n + u * hold;
      hdec[bb * 256 + jg] = hnew;
      hn_s[jl * 33 + bb] = hnew;
      int bo = (bb * 512 + jg * 2) ^ ((bb & 7) << 4);
      hbf_w[bo >> 1] = f2b(hnew);
    }
  }
  __syncthreads();

  // fc partial: recon[b][t][d] += hnew . fc_w(slice)
  if (tid < 32) {
    const float* fw = fcw + d * 256 + s * 32;
    float acc = 0.f;
    #pragma unroll
    for (int jl = 0; jl < 32; ++jl) acc += hn_s[jl * 33 + tid] * fw[jl];
    atomicAdd(&out[(tid * NT + t) * ND + d], acc);
  }
}

extern "C" void kernel_launch(void* const* d_in, const int* in_sizes, int n_in,
                              void* d_out, int out_size, void* d_ws, size_t ws_size,
                              hipStream_t stream) {
  const float* x_past = (const float*)d_in[0];
  const float* x_curr = (const float*)d_in[1];
  const float* eps    = (const float*)d_in[2];
  const float* eWih   = (const float*)d_in[3];
  const float* ebih   = (const float*)d_in[4];
  const float* eWhh   = (const float*)d_in[5];
  const float* ebhh   = (const float*)d_in[6];
  const float* muw    = (const float*)d_in[7];
  const float* mub    = (const float*)d_in[8];
  const float* lsw    = (const float*)d_in[9];
  const float* lsb    = (const float*)d_in[10];
  const float* refw   = (const float*)d_in[11];
  const float* refb   = (const float*)d_in[12];
  const float* Win    = (const float*)d_in[13];
  const float* hWih   = (const float*)d_in[14];
  const float* hbih   = (const float*)d_in[15];
  const float* hWhh   = (const float*)d_in[16];
  const float* hbhh   = (const float*)d_in[17];
  const float* fcw    = (const float*)d_in[18];
  const float* fcb    = (const float*)d_in[19];
  float* ws  = (float*)d_ws;
  float* out = (float*)d_out;

  if (ws_size < (size_t)WS_FLOATS * 4) return;

  k_pre   <<<2048, 256, 0, stream>>>(hWhh, hbih, hbhh, eWhh, eWih, ws);
  k_wcomb <<<768, 256, 0, stream>>>(Win, hWih, ws);
  k_misc  <<<384, 256, 0, stream>>>(x_past, x_curr, fcb, ws, out);
  k_gi_enc<<<NB * NT, 256, 0, stream>>>(x_past, ebih, ws);
  k_enc   <<<NB, 256, 0, stream>>>(ebhh, ws);
  k_latent<<<NB, 256, 0, stream>>>(muw, mub, lsw, lsb, refw, refb, eps, ws, out);
  k_hbf0  <<<512, 256, 0, stream>>>(ws);
  for (int t = 0; t < NT; ++t)
    k_step2<<<256, 384, 0, stream>>>(fcw, ws, out, t);
}

// Round 3
// 1110.728 us; speedup vs baseline: 1.3178x; 1.3178x over previous
//
#include <hip/hip_runtime.h>
#include <math.h>

constexpr int NB = 32, NT = 64, ND = 32, NH = 256, NZ = 64, NG = 768;

// ---- ws layout (float offsets; u16 regions noted) --------------------------
constexpr long long OFF_HENC   = 0;                               // [32][256] f32
constexpr long long OFF_H0     = OFF_HENC + NB * NH;              // [32][256] f32
constexpr long long OFF_HDEC   = OFF_H0 + NB * NH;                // [32d][32b][256] f32 master h
constexpr long long OFF_BCMB   = OFF_HDEC + (long long)ND * NB * NH; // [32d][2][256]
constexpr long long OFF_BIN    = OFF_BCMB + ND * 2 * NH;          // [32d][256]
constexpr long long OFF_BHN    = OFF_BIN + ND * NH;               // [32d][256]
constexpr long long OFF_WHHIMG = OFF_BHN + ND * NH;               // u16: 256 pages x 24576 (swizzled bf16)
constexpr long long OFF_WCIMG  = OFF_WHHIMG + (long long)256 * 24576 / 2; // u16: 256 x 3072
constexpr long long OFF_DINIMG = OFF_WCIMG + 256 * 3072 / 2;      // u16: 64 x 1024
constexpr long long OFF_HBF    = OFF_DINIMG + 64 * 1024 / 2;      // u16: 2 par x 32 d x 8192
constexpr long long OFF_EWIMG  = OFF_HBF + 2 * 32 * 8192 / 2;     // u16: 48rt x 9kc x 1024B frag-ordered
constexpr long long WS_FLOATS  = OFF_EWIMG + (long long)48 * 9 * 1024 / 2; // ~17.5 MB

typedef __attribute__((ext_vector_type(8))) short bf16x8;
typedef __attribute__((ext_vector_type(4))) float f32x4;

__device__ __forceinline__ float sigm(float x) { return 1.f / (1.f + __expf(-x)); }
__device__ __forceinline__ ushort f2b(float x) {
  unsigned u = __float_as_uint(x);
  unsigned r = (u + 0x7FFFu + ((u >> 16) & 1u)) >> 16;
  return (ushort)r;
}

// ---------------- k_pre: decoder Whh images + biases + encoder frag image ----
__global__ void k_pre(const float* __restrict__ hWhh, const float* __restrict__ hbih,
                      const float* __restrict__ hbhh, const float* __restrict__ eWhh,
                      const float* __restrict__ eWih, float* __restrict__ ws) {
  int stride = gridDim.x * blockDim.x;
  int idx = blockIdx.x * blockDim.x + threadIdx.x;
  // (1) decoder Whh bf16 swizzled images: 256 pages x 12288 dwords
  unsigned* img = (unsigned*)(ws + OFF_WHHIMG);
  const int totw = 256 * 12288;
  for (int i = idx; i < totw; i += stride) {
    int p = i / 12288, lw = i - p * 12288;
    int d = p >> 3, s = p & 7;
    int byte = lw * 4;
    int lr = byte >> 9;
    int nominal = byte ^ ((lr & 7) << 4);
    int k0 = (nominal & 511) >> 1;
    int g = (lr >> 5) * 256 + s * 32 + (lr & 31);
    const float* src = hWhh + ((long long)(d * NG + g)) * NH + k0;
    unsigned lo = f2b(src[0]), hi = f2b(src[1]);
    img[i] = lo | (hi << 16);
  }
  // (2) decoder biases
  for (int i = idx; i < ND * NH; i += stride) {
    int d = i >> 8, j = i & 255;
    const float* bi = hbih + d * NG;
    const float* bh = hbhh + d * NG;
    ws[OFF_BCMB + d * 512 + j]       = bi[j] + bh[j];
    ws[OFF_BCMB + d * 512 + 256 + j] = bi[256 + j] + bh[256 + j];
    ws[OFF_BIN + i] = bi[512 + j];
    ws[OFF_BHN + i] = bh[512 + j];
  }
  // (3) encoder frag-ordered image: [rt 0..47][kc 0..8] 1KB frags
  unsigned* eimg = (unsigned*)(ws + OFF_EWIMG);
  const int tote = 48 * 9 * 256;
  for (int i = idx; i < tote; i += stride) {
    int frag = i >> 8, widx = i & 255;
    int rt = frag / 9, kc = frag - rt * 9;
    int l = widx >> 2, jp = (widx & 3) * 2;
    int row = rt * 16 + (l & 15);
    float v0, v1;
    if (kc < 8) {
      int k0 = kc * 32 + (l >> 4) * 8 + jp;
      v0 = eWhh[row * 256 + k0];
      v1 = eWhh[row * 256 + k0 + 1];
    } else {
      int koff = (l >> 4) * 8 + jp;
      v0 = eWih[row * 32 + koff];
      v1 = eWih[row * 32 + koff + 1];
    }
    unsigned lo = f2b(v0), hi = f2b(v1);
    eimg[i] = lo | (hi << 16);
  }
}

// ---------------- k_wcomb: Wcomb[d][g][dd] = sum_h Wih[g,h]*Win[dd,h] --------
__global__ __launch_bounds__(256)
void k_wcomb(const float* __restrict__ Win, const float* __restrict__ hWih,
             float* __restrict__ ws) {
  __shared__ float wd_s[32 * 257];
  __shared__ float wih_s[32 * 257];
  int blk = blockIdx.x;            // 768 = 32 d x 24 gsec
  int d = blk / 24, gsec = blk - d * 24;
  int tid = threadIdx.x;
  for (int i = tid; i < 32 * 256; i += 256) {
    int r = i >> 8, h = i & 255;
    wd_s[r * 257 + h]  = Win[((long long)(d * 32 + r)) * 256 + h];
    wih_s[r * 257 + h] = hWih[((long long)(d * NG + gsec * 32 + r)) * 256 + h];
  }
  __syncthreads();
  ushort* wcimg = (ushort*)(ws + OFF_WCIMG);
  for (int o = tid; o < 1024; o += 256) {
    int gl = o >> 5, dd = o & 31;
    float acc = 0.f;
    #pragma unroll 4
    for (int h = 0; h < 256; ++h) acc += wih_s[gl * 257 + h] * wd_s[dd * 257 + h];
    int gloc = gsec * 32 + gl;
    int sec = gloc >> 8, s = (gloc & 255) >> 5, lr = sec * 32 + (gloc & 31);
    int off = (lr * 64 + dd * 2) ^ ((lr & 3) << 4);
    wcimg[(d * 8 + s) * 3072 + (off >> 1)] = f2b(acc);
  }
}

// ---------------- k_misc: recon init (fc_b) + din bf16 swizzled pages --------
__global__ void k_misc(const float* __restrict__ xp, const float* __restrict__ xc,
                       const float* __restrict__ fcb, float* __restrict__ ws,
                       float* __restrict__ out) {
  int idx = blockIdx.x * blockDim.x + threadIdx.x;
  if (idx < 65536) {
    out[idx] = fcb[idx & 31];
  } else {
    int i2 = idx - 65536;
    int t = i2 >> 9, lw = i2 & 511;
    int byte = lw * 4;
    int b = byte >> 6;
    int nominal = byte ^ ((b & 3) << 4);
    int dd0 = (nominal & 63) >> 1;
    float v0, v1;
    if (t == 0) {
      v0 = xp[(b * NT + 63) * ND + dd0];
      v1 = xp[(b * NT + 63) * ND + dd0 + 1];
    } else {
      v0 = xc[(b * NT + (t - 1)) * ND + dd0];
      v1 = xc[(b * NT + (t - 1)) * ND + dd0 + 1];
    }
    unsigned lo = f2b(v0), hi = f2b(v1);
    ((unsigned*)(ws + OFF_DINIMG))[i2] = lo | (hi << 16);
  }
}

// ---------------- k_enc2: persistent encoder, 2 blocks x 16 batches ----------
// gates = [h ; x_t] @ [Whh ; Wih]^T via K=288 MFMA; weights streamed as
// frag-ordered bf16 image (coalesced dwordx4/lane); h f32 master in regs.
__global__ __launch_bounds__(512)
void k_enc2(const float* __restrict__ xp, const float* __restrict__ ebih,
            const float* __restrict__ ebhh, float* __restrict__ ws) {
  __shared__ float rz_s[512 * 17];
  __shared__ float in_s[256 * 17];
  __shared__ float ahn_s[256 * 17];
  __shared__ __align__(16) char h_lds[2][8192];
  __shared__ __align__(16) char x_lds[1024];
  __shared__ float bias_s[1536];

  const int bg = blockIdx.x;                 // 0,1
  const int tid = threadIdx.x, lane = tid & 63, w = tid >> 6;
  const uint4* wp = (const uint4*)((const ushort*)(ws + OFF_EWIMG));

  for (int i = tid; i < 1536; i += 512) bias_s[i] = (i < 768) ? ebih[i] : ebhh[i - 768];
  for (int i = tid; i < 2048; i += 512) ((unsigned*)h_lds)[i] = 0;  // zero parity 0
  float hreg[8];
  #pragma unroll
  for (int q = 0; q < 8; ++q) hreg[q] = 0.f;

  const int colb = lane & 15;
  const int kb16 = (lane >> 4) * 16;
  const int rtbase = w * 6;

  for (int t = 0; t < 64; ++t) {
    const int par = t & 1;
    // stage x_t (bf16, swizzled) -- safe vs concurrent gate math of t-1
    {
      int b = tid >> 5, dd = tid & 31;
      float v = xp[(((bg * 16 + b) * 64) + t) * 32 + dd];
      int bo = (b * 64 + dd * 2) ^ ((b & 3) << 4);
      *(ushort*)(x_lds + bo) = f2b(v);
    }
    __syncthreads();

    // B-frags (shared across this wave's 6 row-tiles)
    bf16x8 bf[9];
    #pragma unroll
    for (int kc = 0; kc < 8; ++kc)
      bf[kc] = *(const bf16x8*)(h_lds[par] + ((colb * 512 + kc * 64 + kb16) ^ ((colb & 7) << 4)));
    bf[8] = *(const bf16x8*)(x_lds + ((colb * 64 + kb16) ^ ((colb & 3) << 4)));

    // A-frag ping-pong over row-tiles
    uint4 fA[9], fN[9];
    #pragma unroll
    for (int kc = 0; kc < 9; ++kc) fA[kc] = wp[(rtbase * 9 + kc) * 64 + lane];
    #pragma unroll
    for (int r = 0; r < 6; ++r) {
      int rt = rtbase + r;
      if (r < 5) {
        #pragma unroll
        for (int kc = 0; kc < 9; ++kc) fN[kc] = wp[((rt + 1) * 9 + kc) * 64 + lane];
      }
      f32x4 a = {0.f, 0.f, 0.f, 0.f};
      #pragma unroll
      for (int kc = 0; kc < 8; ++kc)
        a = __builtin_amdgcn_mfma_f32_16x16x32_bf16(*(const bf16x8*)&fA[kc], bf[kc], a, 0, 0, 0);
      f32x4 ai = {0.f, 0.f, 0.f, 0.f};
      ai = __builtin_amdgcn_mfma_f32_16x16x32_bf16(*(const bf16x8*)&fA[8], bf[8], ai, 0, 0, 0);
      int r0 = rt * 16 + (lane >> 4) * 4;
      if (rt < 32) {     // r,z rows: gi and gh combine
        #pragma unroll
        for (int rg = 0; rg < 4; ++rg) rz_s[(r0 + rg) * 17 + colb] = a[rg] + ai[rg];
      } else {           // n rows: keep separate
        #pragma unroll
        for (int rg = 0; rg < 4; ++rg) {
          in_s[(r0 - 512 + rg) * 17 + colb]  = ai[rg];
          ahn_s[(r0 - 512 + rg) * 17 + colb] = a[rg];
        }
      }
      #pragma unroll
      for (int kc = 0; kc < 9; ++kc) fA[kc] = fN[kc];
    }
    __syncthreads();

    // gate math: 4096 items, thread owns fixed (j,b) pairs; h master in regs
    #pragma unroll
    for (int it = 0; it < 8; ++it) {
      int idx = tid + it * 512;
      int b = idx & 15, j = idx >> 4;
      float pr = rz_s[j * 17 + b] + bias_s[j] + bias_s[768 + j];
      float pz = rz_s[(256 + j) * 17 + b] + bias_s[256 + j] + bias_s[1024 + j];
      float pni = in_s[j * 17 + b] + bias_s[512 + j];
      float pnh = ahn_s[j * 17 + b] + bias_s[1280 + j];
      float r = sigm(pr), u = sigm(pz);
      float n = tanhf(pni + r * pnh);
      float h = (1.f - u) * n + u * hreg[it];
      hreg[it] = h;
      int bo = (b * 512 + j * 2) ^ ((b & 7) << 4);
      *(ushort*)(h_lds[par ^ 1] + bo) = f2b(h);
    }
    __syncthreads();
  }
  // final hidden -> HENC
  #pragma unroll
  for (int it = 0; it < 8; ++it) {
    int idx = tid + it * 512;
    int b = idx & 15, j = idx >> 4;
    ws[OFF_HENC + (bg * 16 + b) * 256 + j] = hreg[it];
  }
}

// ---------------- latent ------------------------------------------------------
__global__ __launch_bounds__(256)
void k_latent(const float* __restrict__ muw, const float* __restrict__ mub,
              const float* __restrict__ lsw, const float* __restrict__ lsb,
              const float* __restrict__ refw, const float* __restrict__ refb,
              const float* __restrict__ eps, float* __restrict__ ws,
              float* __restrict__ out) {
  __shared__ float hs[NH];
  __shared__ float mu_s[NZ];
  __shared__ float ls_s[NZ];
  __shared__ float zs[NZ];
  int b = blockIdx.x, tid = threadIdx.x;
  hs[tid] = ws[OFF_HENC + b * NH + tid];
  __syncthreads();
  if (tid < 128) {
    int zi = tid & 63;
    const float* w = (tid < 64 ? muw : lsw) + zi * NH;
    float acc = 0.f;
    #pragma unroll 4
    for (int k = 0; k < NH; ++k) acc += w[k] * hs[k];
    if (tid < 64) {
      acc += mub[zi];
      out[NB * NT * ND + b * NZ + zi] = acc;
      mu_s[zi] = acc;
    } else {
      acc += lsb[zi];
      out[NB * NT * ND + NB * NZ + b * NZ + zi] = acc;
      ls_s[zi] = acc;
    }
  }
  __syncthreads();
  if (tid < 64) zs[tid] = mu_s[tid] + eps[b * NZ + tid] * __expf(ls_s[tid]);
  __syncthreads();
  {
    const float* w = refw + tid * NZ;
    float acc = 0.f;
    #pragma unroll 4
    for (int q = 0; q < NZ; ++q) acc += w[q] * zs[q];
    ws[OFF_H0 + b * NH + tid] = tanhf(acc + refb[tid]);
  }
}

// ---------------- k_hbf0: h0 -> bf16 swizzled pages (parity 0) ----------------
__global__ void k_hbf0(float* __restrict__ ws) {
  int idx = blockIdx.x * blockDim.x + threadIdx.x;   // 32 x 4096 dwords
  int d = idx >> 12, lw = idx & 4095;
  int byte = lw * 4;
  int bb = byte >> 9;
  int nominal = byte ^ ((bb & 7) << 4);
  int j0 = (nominal & 511) >> 1;
  const float* h0 = ws + OFF_H0 + bb * 256;
  unsigned lo = f2b(h0[j0]), hi = f2b(h0[j0 + 1]);
  ((unsigned*)(ws + OFF_HBF))[d * 4096 + lw] = lo | (hi << 16);
}

// ---------------- decoder step: 256 blocks = 8 slices x 32 heads --------------
__global__ __launch_bounds__(384)
void k_step2(const float* __restrict__ fcw, float* __restrict__ ws,
             float* __restrict__ out, int t) {
  __shared__ __align__(16) char lds[49152 + 6144 + 16384 + 2048];
  __shared__ float rz_s[64 * 33];
  __shared__ float in_s[32 * 33];
  __shared__ float ahn_s[32 * 33];
  __shared__ float hn_s[32 * 33];

  char* l_whh = lds;
  char* l_wc  = lds + 49152;
  char* l_hbf = lds + 49152 + 6144;
  char* l_din = lds + 49152 + 6144 + 16384;

  const int d = blockIdx.x & 31, s = blockIdx.x >> 5;
  const int tid = threadIdx.x, lane = tid & 63, w = tid >> 6;

  const ushort* whh_img = (const ushort*)(ws + OFF_WHHIMG) + (long long)(d * 8 + s) * 24576;
  const ushort* wc_img  = (const ushort*)(ws + OFF_WCIMG) + (d * 8 + s) * 3072;
  const ushort* hbf_r   = (const ushort*)(ws + OFF_HBF) + ((t & 1) * 32 + d) * 8192;
  const ushort* din_img = (const ushort*)(ws + OFF_DINIMG) + t * 1024;

  {  // staging: 4608 x 16B chunks (linear; images pre-swizzled)
    const uint4* s_whh = (const uint4*)whh_img;
    const uint4* s_wc  = (const uint4*)wc_img;
    const uint4* s_hbf = (const uint4*)hbf_r;
    const uint4* s_din = (const uint4*)din_img;
    uint4* d_whh = (uint4*)l_whh; uint4* d_wc = (uint4*)l_wc;
    uint4* d_hbf = (uint4*)l_hbf; uint4* d_din = (uint4*)l_din;
    for (int c = tid; c < 4608; c += 384) {
      if (c < 3072)      d_whh[c] = s_whh[c];
      else if (c < 3456) d_wc[c - 3072] = s_wc[c - 3072];
      else if (c < 4480) d_hbf[c - 3456] = s_hbf[c - 3456];
      else               d_din[c - 4480] = s_din[c - 4480];
    }
  }
  __syncthreads();

  const int ct = w & 1, rtb = w >> 1;
  const int colL = lane & 15;
  const int kb = (lane >> 4) * 16;
  #pragma unroll
  for (int i = 0; i < 2; ++i) {
    int rtx = rtb + 3 * i;
    int rowW = rtx * 16 + colL;
    int rowB = ct * 16 + colL;
    f32x4 ah = {0.f, 0.f, 0.f, 0.f};
    #pragma unroll
    for (int kc = 0; kc < 8; ++kc) {
      int ka = kc * 64 + kb;
      bf16x8 av = *(const bf16x8*)(l_whh + (((rowW * 512 + ka)) ^ ((rowW & 7) << 4)));
      bf16x8 bv = *(const bf16x8*)(l_hbf + (((rowB * 512 + ka)) ^ ((rowB & 7) << 4)));
      ah = __builtin_amdgcn_mfma_f32_16x16x32_bf16(av, bv, ah, 0, 0, 0);
    }
    f32x4 zero = {0.f, 0.f, 0.f, 0.f};
    bf16x8 aw = *(const bf16x8*)(l_wc + (((rowW * 64 + kb)) ^ ((rowW & 3) << 4)));
    bf16x8 bd = *(const bf16x8*)(l_din + (((rowB * 64 + kb)) ^ ((rowB & 3) << 4)));
    f32x4 ai = __builtin_amdgcn_mfma_f32_16x16x32_bf16(aw, bd, zero, 0, 0, 0);
    int r0 = rtx * 16 + (lane >> 4) * 4;
    int col = ct * 16 + colL;
    #pragma unroll
    for (int rg = 0; rg < 4; ++rg) {
      int lr = r0 + rg;
      if (lr < 64) rz_s[lr * 33 + col] = ah[rg] + ai[rg];
      else { in_s[(lr - 64) * 33 + col] = ai[rg]; ahn_s[(lr - 64) * 33 + col] = ah[rg]; }
    }
  }
  __syncthreads();

  const float* bcmb = ws + OFF_BCMB + d * 512;
  const float* bin  = ws + OFF_BIN + d * 256;
  const float* bhn  = ws + OFF_BHN + d * 256;
  float* hdec = ws + OFF_HDEC + (long long)d * NB * NH;
  const float* h0 = ws + OFF_H0;
  ushort* hbf_w = (ushort*)(ws + OFF_HBF) + (((t + 1) & 1) * 32 + d) * 8192;

  for (int base = 0; base < 1024; base += 384) {
    int idx = base + tid;
    if (idx < 1024) {
      int bb = idx >> 5, jl = idx & 31, jg = s * 32 + jl;
      float pr = rz_s[jl * 33 + bb] + bcmb[jg];
      float pz = rz_s[(32 + jl) * 33 + bb] + bcmb[256 + jg];
      float pni = in_s[jl * 33 + bb] + bin[jg];
      float pnh = ahn_s[jl * 33 + bb] + bhn[jg];
      float r = sigm(pr), u = sigm(pz);
      float n = tanhf(pni + r * pnh);
      float hold = (t == 0) ? h0[bb * 256 + jg] : hdec[bb * 256 + jg];
      float hnew = (1.f - u) * n + u * hold;
      hdec[bb * 256 + jg] = hnew;
      hn_s[jl * 33 + bb] = hnew;
      int bo = (bb * 512 + jg * 2) ^ ((bb & 7) << 4);
      hbf_w[bo >> 1] = f2b(hnew);
    }
  }
  __syncthreads();

  if (tid < 32) {
    const float* fw = fcw + d * 256 + s * 32;
    float acc = 0.f;
    #pragma unroll
    for (int jl = 0; jl < 32; ++jl) acc += hn_s[jl * 33 + tid] * fw[jl];
    atomicAdd(&out[(tid * NT + t) * ND + d], acc);
  }
}

extern "C" void kernel_launch(void* const* d_in, const int* in_sizes, int n_in,
                              void* d_out, int out_size, void* d_ws, size_t ws_size,
                              hipStream_t stream) {
  const float* x_past = (const float*)d_in[0];
  const float* x_curr = (const float*)d_in[1];
  const float* eps    = (const float*)d_in[2];
  const float* eWih   = (const float*)d_in[3];
  const float* ebih   = (const float*)d_in[4];
  const float* eWhh   = (const float*)d_in[5];
  const float* ebhh   = (const float*)d_in[6];
  const float* muw    = (const float*)d_in[7];
  const float* mub    = (const float*)d_in[8];
  const float* lsw    = (const float*)d_in[9];
  const float* lsb    = (const float*)d_in[10];
  const float* refw   = (const float*)d_in[11];
  const float* refb   = (const float*)d_in[12];
  const float* Win    = (const float*)d_in[13];
  const float* hWih   = (const float*)d_in[14];
  const float* hbih   = (const float*)d_in[15];
  const float* hWhh   = (const float*)d_in[16];
  const float* hbhh   = (const float*)d_in[17];
  const float* fcw    = (const float*)d_in[18];
  const float* fcb    = (const float*)d_in[19];
  float* ws  = (float*)d_ws;
  float* out = (float*)d_out;

  if (ws_size < (size_t)WS_FLOATS * 4) return;

  k_pre   <<<2048, 256, 0, stream>>>(hWhh, hbih, hbhh, eWhh, eWih, ws);
  k_wcomb <<<768, 256, 0, stream>>>(Win, hWih, ws);
  k_misc  <<<384, 256, 0, stream>>>(x_past, x_curr, fcb, ws, out);
  k_enc2  <<<2, 512, 0, stream>>>(x_past, ebih, ebhh, ws);
  k_latent<<<NB, 256, 0, stream>>>(muw, mub, lsw, lsb, refw, refb, eps, ws, out);
  k_hbf0  <<<512, 256, 0, stream>>>(ws);
  for (int t = 0; t < NT; ++t)
    k_step2<<<256, 384, 0, stream>>>(fcw, ws, out, t);
}